// Round 1
// baseline (2567.312 us; speedup 1.0000x reference)
//
#include <hip/hip_runtime.h>
#include <cstdint>
#include <cstddef>

#define TOPK 50
#define B_ROWS 8192
#define IN_DIM 1024
#define HID_DIM 16384

typedef unsigned short u16;
typedef __attribute__((ext_vector_type(8))) short bf16x8;
typedef __attribute__((ext_vector_type(4))) float f32x4;

// ---------- helpers ----------
__device__ inline u16 f2bf_rne(float f) {
  unsigned u = __float_as_uint(f);
  unsigned r = 0x7FFFu + ((u >> 16) & 1u);
  return (u16)((u + r) >> 16);
}
__device__ inline float bf2f(u16 h) { return __uint_as_float(((unsigned)h) << 16); }

__device__ inline void gload16(const void* g, void* l) {
  __builtin_amdgcn_global_load_lds(
      (const __attribute__((address_space(1))) void*)g,
      (__attribute__((address_space(3))) void*)l, 16, 0, 0);
}

__device__ inline unsigned key_of(float f) {
  unsigned u = __float_as_uint(f);
  return u ^ ((unsigned)((int)u >> 31) | 0x80000000u);
}

// ---------- split f32 -> bf16 h/m/l ----------
__global__ __launch_bounds__(256)
void split3_kernel(const float* __restrict__ in, u16* __restrict__ h,
                   u16* __restrict__ m, u16* __restrict__ l, int n4) {
  int i = blockIdx.x * 256 + threadIdx.x;
  const int stride = gridDim.x * 256;
  for (; i < n4; i += stride) {
    const float4 f = reinterpret_cast<const float4*>(in)[i];
    float vs[4] = {f.x, f.y, f.z, f.w};
    u16 hh[4], mm[4], ll[4];
#pragma unroll
    for (int j = 0; j < 4; ++j) {
      float v = vs[j];
      u16 a = f2bf_rne(v); float fa = bf2f(a);
      u16 b = f2bf_rne(v - fa); float fb = bf2f(b);
      u16 c = f2bf_rne(v - fa - fb);
      hh[j] = a; mm[j] = b; ll[j] = c;
    }
    reinterpret_cast<ushort4*>(h)[i] = make_ushort4(hh[0], hh[1], hh[2], hh[3]);
    reinterpret_cast<ushort4*>(m)[i] = make_ushort4(mm[0], mm[1], mm[2], mm[3]);
    reinterpret_cast<ushort4*>(l)[i] = make_ushort4(ll[0], ll[1], ll[2], ll[3]);
  }
}

// ---------- transpose W_dec [1024][16384] -> WdT [16384][1024] ----------
__global__ __launch_bounds__(256)
void transpose_kernel(const float* __restrict__ Wd, float* __restrict__ WdT) {
  __shared__ float tile[32][33];
  const int h0 = blockIdx.x * 32;
  const int o0 = blockIdx.y * 32;
  const int lx = threadIdx.x & 31;
  const int ly = threadIdx.x >> 5;  // 0..7
#pragma unroll
  for (int r = 0; r < 32; r += 8)
    tile[ly + r][lx] = Wd[(size_t)(o0 + ly + r) * HID_DIM + h0 + lx];
  __syncthreads();
#pragma unroll
  for (int r = 0; r < 32; r += 8)
    WdT[(size_t)(h0 + ly + r) * IN_DIM + o0 + lx] = tile[lx][ly + r];
}

// ---------- GEMM: z = x @ W_enc^T via 6-term bf16 split MFMA ----------
// 128x128 tile, BK=32, 4 waves (2x2), each wave 64x64 (4x4 frags of 16x16x32)
__global__ __launch_bounds__(256, 2)
void gemm6_kernel(const u16* __restrict__ xh, const u16* __restrict__ xm, const u16* __restrict__ xl,
                  const u16* __restrict__ wh, const u16* __restrict__ wm, const u16* __restrict__ wl,
                  float* __restrict__ z) {
  __shared__ u16 sA[3][128 * 32];
  __shared__ u16 sB[3][128 * 32];
  const int tid = threadIdx.x;
  const int lane = tid & 63;
  const int wave = tid >> 6;
  const int wr = (wave >> 1) * 64;
  const int wc = (wave & 1) * 64;
  const int m0 = blockIdx.y * 128;
  const int n0 = blockIdx.x * 128;

  // staging: thread t stages 16B chunk t (and t+256). row = t/4, k-slot = t%4,
  // with XOR swizzle on the k-slot: source k = ((t&3) ^ ((row>>1)&3))*8
  const int srow = tid >> 2;
  const int scol = (((tid & 3) ^ ((srow >> 1) & 3)) * 8);

  const u16* gA[3] = {xh, xm, xl};
  const u16* gB[3] = {wh, wm, wl};

  const size_t aoff = (size_t)(m0 + srow) * IN_DIM + scol;
  const size_t boff = (size_t)(n0 + srow) * IN_DIM + scol;

  f32x4 acc[4][4] = {};

  const int rsel = lane & 15;
  const int ksel = (lane >> 4) * 8;

  for (int k0 = 0; k0 < IN_DIM; k0 += 32) {
#pragma unroll
    for (int s = 0; s < 3; ++s) {
      gload16(gA[s] + aoff + k0,                 &sA[s][tid * 8]);
      gload16(gA[s] + aoff + k0 + 64 * IN_DIM,   &sA[s][2048 + tid * 8]);
      gload16(gB[s] + boff + k0,                 &sB[s][tid * 8]);
      gload16(gB[s] + boff + k0 + 64 * IN_DIM,   &sB[s][2048 + tid * 8]);
    }
    __syncthreads();
    bf16x8 a[3][4], b[3][4];
#pragma unroll
    for (int t = 0; t < 4; ++t) {
      const int ra = wr + t * 16 + rsel;
      const int rb = wc + t * 16 + rsel;
      const int ka = ksel ^ (((ra >> 1) & 3) * 8);
      const int kb = ksel ^ (((rb >> 1) & 3) * 8);
#pragma unroll
      for (int s = 0; s < 3; ++s) {
        a[s][t] = *reinterpret_cast<const bf16x8*>(&sA[s][ra * 32 + ka]);
        b[s][t] = *reinterpret_cast<const bf16x8*>(&sB[s][rb * 32 + kb]);
      }
    }
#pragma unroll
    for (int mt = 0; mt < 4; ++mt)
#pragma unroll
      for (int nt = 0; nt < 4; ++nt) {
        f32x4 c = acc[mt][nt];
        c = __builtin_amdgcn_mfma_f32_16x16x32_bf16(a[0][mt], b[0][nt], c, 0, 0, 0); // hh
        c = __builtin_amdgcn_mfma_f32_16x16x32_bf16(a[0][mt], b[1][nt], c, 0, 0, 0); // hm
        c = __builtin_amdgcn_mfma_f32_16x16x32_bf16(a[1][mt], b[0][nt], c, 0, 0, 0); // mh
        c = __builtin_amdgcn_mfma_f32_16x16x32_bf16(a[0][mt], b[2][nt], c, 0, 0, 0); // hl
        c = __builtin_amdgcn_mfma_f32_16x16x32_bf16(a[1][mt], b[1][nt], c, 0, 0, 0); // mm
        c = __builtin_amdgcn_mfma_f32_16x16x32_bf16(a[2][mt], b[0][nt], c, 0, 0, 0); // lh
        acc[mt][nt] = c;
      }
    __syncthreads();
  }
  // epilogue: C/D layout col=lane&15, row=(lane>>4)*4+j  (guide m89-verified)
  const int col = lane & 15;
  const int r0 = (lane >> 4) * 4;
#pragma unroll
  for (int mt = 0; mt < 4; ++mt)
#pragma unroll
    for (int nt = 0; nt < 4; ++nt)
#pragma unroll
      for (int j = 0; j < 4; ++j) {
        const int rr = m0 + wr + mt * 16 + r0 + j;
        const int cc = n0 + wc + nt * 16 + col;
        z[(size_t)rr * HID_DIM + cc] = acc[mt][nt][j];
      }
}

// ---------- block-wide exclusive scan over 256 threads ----------
__device__ inline int excl_scan256(int v, unsigned* s, int tid) {
  s[tid] = (unsigned)v;
  __syncthreads();
  for (int off = 1; off < 256; off <<= 1) {
    unsigned add = (tid >= off) ? s[tid - off] : 0u;
    __syncthreads();
    s[tid] += add;
    __syncthreads();
  }
  int incl = (int)s[tid];
  __syncthreads();
  return incl - v;
}

// ---------- exact top-50 per row: radix select + in-place sparsify ----------
__global__ __launch_bounds__(256)
void topk_kernel(float* __restrict__ z, int* __restrict__ idxL, float* __restrict__ valL) {
  __shared__ float sv[HID_DIM];        // 64 KiB
  __shared__ unsigned shist[4][256];   // per-wave histogram copies
  __shared__ unsigned sScan[256];
  __shared__ unsigned sBcast[2];
  const int tid = threadIdx.x;
  const int wv = tid >> 6;
  const size_t row = blockIdx.x;
  float* zrow = z + row * HID_DIM;

  for (int i = tid; i < HID_DIM / 4; i += 256)
    reinterpret_cast<float4*>(sv)[i] = reinterpret_cast<const float4*>(zrow)[i];
  __syncthreads();

  unsigned prefix = 0, Kr = TOPK;
  for (int p = 3; p >= 0; --p) {
    shist[0][tid] = 0; shist[1][tid] = 0; shist[2][tid] = 0; shist[3][tid] = 0;
    __syncthreads();
    const int shift = p * 8;
    const unsigned pmask = (p == 3) ? 0u : (0xFFFFFFFFu << (shift + 8));
    for (int i = tid; i < HID_DIM; i += 256) {
      unsigned u = key_of(sv[i]);
      if ((u & pmask) == prefix)
        atomicAdd(&shist[wv][(u >> shift) & 0xFF], 1u);
    }
    __syncthreads();
    sScan[tid] = shist[0][tid] + shist[1][tid] + shist[2][tid] + shist[3][tid];
    __syncthreads();
    // suffix sum S[t] = sum_{i>=t} hist[i]
    for (int off = 1; off < 256; off <<= 1) {
      unsigned add = (tid + off < 256) ? sScan[tid + off] : 0u;
      __syncthreads();
      sScan[tid] += add;
      __syncthreads();
    }
    unsigned S = sScan[tid];
    unsigned Snext = (tid < 255) ? sScan[tid + 1] : 0u;
    if (S >= Kr && Snext < Kr) {
      sBcast[0] = prefix | ((unsigned)tid << shift);
      sBcast[1] = Kr - Snext;
    }
    __syncthreads();
    prefix = sBcast[0];
    Kr = sBcast[1];
    __syncthreads();
  }
  const unsigned T = prefix;           // exact key of 50th-largest
  const int nTieKeep = (int)Kr;        // #elems == T to keep (lowest index first)
  const int cGtTotal = TOPK - nTieKeep;

  // per-thread counts over contiguous chunk (deterministic index order)
  const int base = tid * (HID_DIM / 256);
  int cg = 0, ct = 0;
  for (int i = 0; i < HID_DIM / 256; ++i) {
    unsigned u = key_of(sv[base + i]);
    cg += (u > T);
    ct += (u == T);
  }
  int gbase = excl_scan256(cg, sScan, tid);
  int tbase = excl_scan256(ct, sScan, tid);
  int gs = gbase, ts = tbase;
  for (int i = 0; i < HID_DIM / 256; ++i) {
    float v = sv[base + i];
    unsigned u = key_of(v);
    if (u > T) {
      idxL[row * TOPK + gs] = base + i;
      valL[row * TOPK + gs] = v;
      ++gs;
    } else if (u == T) {
      if (ts < nTieKeep) {
        idxL[row * TOPK + cGtTotal + ts] = base + i;
        valL[row * TOPK + cGtTotal + ts] = v;
      }
      ++ts;
    }
  }
  __syncthreads();
  // coalesced sparse write (ties written as 0 here, fixed below)
  for (int i = tid; i < HID_DIM; i += 256) {
    float v = sv[i];
    zrow[i] = (key_of(v) > T) ? v : 0.0f;
  }
  __syncthreads();
  if (tid < nTieKeep) {
    int gi = idxL[row * TOPK + cGtTotal + tid];
    zrow[gi] = valL[row * TOPK + cGtTotal + tid];
  }
}

// ---------- sparse decode: recon = z_sparse @ W_dec^T ----------
__global__ __launch_bounds__(256)
void decode_kernel(const int* __restrict__ idxL, const float* __restrict__ valL,
                   const float* __restrict__ WdT, float* __restrict__ recon) {
  __shared__ int sIdx[TOPK];
  __shared__ float sVal[TOPK];
  const int tid = threadIdx.x;
  const size_t row = blockIdx.x;
  if (tid < TOPK) { sIdx[tid] = idxL[row * TOPK + tid]; sVal[tid] = valL[row * TOPK + tid]; }
  __syncthreads();
  float4 acc = make_float4(0.f, 0.f, 0.f, 0.f);
  const int o = tid * 4;
  for (int j = 0; j < TOPK; ++j) {
    const float4 w4 = *reinterpret_cast<const float4*>(&WdT[(size_t)sIdx[j] * IN_DIM + o]);
    const float v = sVal[j];
    acc.x = fmaf(v, w4.x, acc.x);
    acc.y = fmaf(v, w4.y, acc.y);
    acc.z = fmaf(v, w4.z, acc.z);
    acc.w = fmaf(v, w4.w, acc.w);
  }
  *reinterpret_cast<float4*>(&recon[row * IN_DIM + o]) = acc;
}

// ---------- launch ----------
extern "C" void kernel_launch(void* const* d_in, const int* in_sizes, int n_in,
                              void* d_out, int out_size, void* d_ws, size_t ws_size,
                              hipStream_t stream) {
  const float* x  = (const float*)d_in[0];
  const float* We = (const float*)d_in[1];
  const float* Wd = (const float*)d_in[2];
  float* recon = (float*)d_out;
  float* z = recon + (size_t)B_ROWS * IN_DIM;   // outputs concatenated: recon, z

  char* ws = (char*)d_ws;
  const size_t MB = 1024ull * 1024ull;
  u16* xh = (u16*)(ws + 0 * MB);     // 16 MiB each (8192x1024 bf16)
  u16* xm = (u16*)(ws + 16 * MB);
  u16* xl = (u16*)(ws + 32 * MB);
  u16* wh = (u16*)(ws + 48 * MB);    // 32 MiB each (16384x1024 bf16)
  u16* wmm = (u16*)(ws + 80 * MB);
  u16* wl = (u16*)(ws + 112 * MB);
  float* WdT = (float*)(ws + 144 * MB); // 64 MiB
  int*   idxL = (int*)(ws + 208 * MB);  // 1.6 MiB
  float* valL = (float*)(ws + 210 * MB);// 1.6 MiB

  split3_kernel<<<2048, 256, 0, stream>>>(x, xh, xm, xl, B_ROWS * IN_DIM / 4);
  split3_kernel<<<2048, 256, 0, stream>>>(We, wh, wmm, wl, HID_DIM * IN_DIM / 4);
  transpose_kernel<<<dim3(HID_DIM / 32, IN_DIM / 32), 256, 0, stream>>>(Wd, WdT);
  gemm6_kernel<<<dim3(HID_DIM / 128, B_ROWS / 128), 256, 0, stream>>>(xh, xm, xl, wh, wmm, wl, z);
  topk_kernel<<<B_ROWS, 256, 0, stream>>>(z, idxL, valL);
  decode_kernel<<<B_ROWS, 256, 0, stream>>>(idxL, valL, WdT, recon);
}

// Round 2
// 1953.202 us; speedup vs baseline: 1.3144x; 1.3144x over previous
//
#include <hip/hip_runtime.h>
#include <cstdint>
#include <cstddef>

#define TOPK 50
#define B_ROWS 8192
#define IN_DIM 1024
#define HID_DIM 16384
#define TKT 512   // topk threads

typedef unsigned short u16;
typedef __attribute__((ext_vector_type(8))) short bf16x8;
typedef __attribute__((ext_vector_type(4))) float f32x4;

// ---------- helpers ----------
__device__ inline u16 f2bf_rne(float f) {
  unsigned u = __float_as_uint(f);
  unsigned r = 0x7FFFu + ((u >> 16) & 1u);
  return (u16)((u + r) >> 16);
}
__device__ inline float bf2f(u16 h) { return __uint_as_float(((unsigned)h) << 16); }

__device__ inline void gload16(const void* g, void* l) {
  __builtin_amdgcn_global_load_lds(
      (const __attribute__((address_space(1))) void*)g,
      (__attribute__((address_space(3))) void*)l, 16, 0, 0);
}

__device__ inline unsigned key_of(float f) {
  unsigned u = __float_as_uint(f);
  return u ^ ((unsigned)((int)u >> 31) | 0x80000000u);
}

// ---------- split f32 -> bf16 h/m/l ----------
__global__ __launch_bounds__(256)
void split3_kernel(const float* __restrict__ in, u16* __restrict__ h,
                   u16* __restrict__ m, u16* __restrict__ l, int n4) {
  int i = blockIdx.x * 256 + threadIdx.x;
  const int stride = gridDim.x * 256;
  for (; i < n4; i += stride) {
    const float4 f = reinterpret_cast<const float4*>(in)[i];
    float vs[4] = {f.x, f.y, f.z, f.w};
    u16 hh[4], mm[4], ll[4];
#pragma unroll
    for (int j = 0; j < 4; ++j) {
      float v = vs[j];
      u16 a = f2bf_rne(v); float fa = bf2f(a);
      u16 b = f2bf_rne(v - fa); float fb = bf2f(b);
      u16 c = f2bf_rne(v - fa - fb);
      hh[j] = a; mm[j] = b; ll[j] = c;
    }
    reinterpret_cast<ushort4*>(h)[i] = make_ushort4(hh[0], hh[1], hh[2], hh[3]);
    reinterpret_cast<ushort4*>(m)[i] = make_ushort4(mm[0], mm[1], mm[2], mm[3]);
    reinterpret_cast<ushort4*>(l)[i] = make_ushort4(ll[0], ll[1], ll[2], ll[3]);
  }
}

// ---------- transpose W_dec [1024][16384] -> WdT bf16 [16384][1024] ----------
__global__ __launch_bounds__(256)
void transpose_kernel(const float* __restrict__ Wd, u16* __restrict__ WdT) {
  __shared__ float tile[32][33];
  const int h0 = blockIdx.x * 32;
  const int o0 = blockIdx.y * 32;
  const int lx = threadIdx.x & 31;
  const int ly = threadIdx.x >> 5;  // 0..7
#pragma unroll
  for (int r = 0; r < 32; r += 8)
    tile[ly + r][lx] = Wd[(size_t)(o0 + ly + r) * HID_DIM + h0 + lx];
  __syncthreads();
#pragma unroll
  for (int r = 0; r < 32; r += 8)
    WdT[(size_t)(h0 + ly + r) * IN_DIM + o0 + lx] = f2bf_rne(tile[lx][ly + r]);
}

// ---------- GEMM: z = x @ W_enc^T via 6-term bf16 split MFMA ----------
// 128x128 tile, BK=32, 4 waves (2x2), each wave 64x64 (4x4 frags of 16x16x32)
// Per-output accumulation order is IDENTICAL to round-1 kernel (bit-exact z);
// only the block->tile mapping changed (XCD-aware swizzle).
__global__ __launch_bounds__(256, 2)
void gemm6_kernel(const u16* __restrict__ xh, const u16* __restrict__ xm, const u16* __restrict__ xl,
                  const u16* __restrict__ wh, const u16* __restrict__ wm, const u16* __restrict__ wl,
                  float* __restrict__ z) {
  __shared__ u16 sA[3][128 * 32];
  __shared__ u16 sB[3][128 * 32];
  const int tid = threadIdx.x;
  const int lane = tid & 63;
  const int wave = tid >> 6;
  const int wr = (wave >> 1) * 64;
  const int wc = (wave & 1) * 64;

  // XCD-aware swizzle: 8192 blocks, 8 XCDs. XCD c owns M-panels [8c,8c+8) for
  // ALL N (A-panels: 6MB, resident in its L2/L3 for the whole chunk; B streams).
  const int bid = blockIdx.y * gridDim.x + blockIdx.x;      // 0..8191
  const int swz = (bid & 7) * 1024 + (bid >> 3);            // bijective
  const int mg = swz >> 10;                                 // 0..7
  const int within = swz & 1023;
  const int n_idx = within >> 3;                            // 0..127
  const int m_idx = (within & 7) + mg * 8;                  // 0..63
  const int m0 = m_idx * 128;
  const int n0 = n_idx * 128;

  const int srow = tid >> 2;
  const int scol = (((tid & 3) ^ ((srow >> 1) & 3)) * 8);

  const u16* gA[3] = {xh, xm, xl};
  const u16* gB[3] = {wh, wm, wl};

  const size_t aoff = (size_t)(m0 + srow) * IN_DIM + scol;
  const size_t boff = (size_t)(n0 + srow) * IN_DIM + scol;

  f32x4 acc[4][4] = {};

  const int rsel = lane & 15;
  const int ksel = (lane >> 4) * 8;

  for (int k0 = 0; k0 < IN_DIM; k0 += 32) {
#pragma unroll
    for (int s = 0; s < 3; ++s) {
      gload16(gA[s] + aoff + k0,                 &sA[s][tid * 8]);
      gload16(gA[s] + aoff + k0 + 64 * IN_DIM,   &sA[s][2048 + tid * 8]);
      gload16(gB[s] + boff + k0,                 &sB[s][tid * 8]);
      gload16(gB[s] + boff + k0 + 64 * IN_DIM,   &sB[s][2048 + tid * 8]);
    }
    __syncthreads();
    bf16x8 a[3][4], b[3][4];
#pragma unroll
    for (int t = 0; t < 4; ++t) {
      const int ra = wr + t * 16 + rsel;
      const int rb = wc + t * 16 + rsel;
      const int ka = ksel ^ (((ra >> 1) & 3) * 8);
      const int kb = ksel ^ (((rb >> 1) & 3) * 8);
#pragma unroll
      for (int s = 0; s < 3; ++s) {
        a[s][t] = *reinterpret_cast<const bf16x8*>(&sA[s][ra * 32 + ka]);
        b[s][t] = *reinterpret_cast<const bf16x8*>(&sB[s][rb * 32 + kb]);
      }
    }
#pragma unroll
    for (int mt = 0; mt < 4; ++mt)
#pragma unroll
      for (int nt = 0; nt < 4; ++nt) {
        f32x4 c = acc[mt][nt];
        c = __builtin_amdgcn_mfma_f32_16x16x32_bf16(a[0][mt], b[0][nt], c, 0, 0, 0); // hh
        c = __builtin_amdgcn_mfma_f32_16x16x32_bf16(a[0][mt], b[1][nt], c, 0, 0, 0); // hm
        c = __builtin_amdgcn_mfma_f32_16x16x32_bf16(a[1][mt], b[0][nt], c, 0, 0, 0); // mh
        c = __builtin_amdgcn_mfma_f32_16x16x32_bf16(a[0][mt], b[2][nt], c, 0, 0, 0); // hl
        c = __builtin_amdgcn_mfma_f32_16x16x32_bf16(a[1][mt], b[1][nt], c, 0, 0, 0); // mm
        c = __builtin_amdgcn_mfma_f32_16x16x32_bf16(a[2][mt], b[0][nt], c, 0, 0, 0); // lh
        acc[mt][nt] = c;
      }
    __syncthreads();
  }
  const int col = lane & 15;
  const int r0 = (lane >> 4) * 4;
#pragma unroll
  for (int mt = 0; mt < 4; ++mt)
#pragma unroll
    for (int nt = 0; nt < 4; ++nt)
#pragma unroll
      for (int j = 0; j < 4; ++j) {
        const int rr = m0 + wr + mt * 16 + r0 + j;
        const int cc = n0 + wc + nt * 16 + col;
        z[(size_t)rr * HID_DIM + cc] = acc[mt][nt][j];
      }
}

// ---------- block-wide exclusive scan over TKT threads (wave0 does the work) ----------
__device__ inline int excl_scan_blk(int v, unsigned* s, int tid) {
  s[tid] = (unsigned)v;
  __syncthreads();
  if (tid < 64) {
    const int G = TKT / 64;  // 8 values per lane
    unsigned x[G];
    unsigned run = 0;
#pragma unroll
    for (int j = 0; j < G; ++j) { unsigned t = s[tid * G + j]; x[j] = run; run += t; }
    unsigned S = run;
#pragma unroll
    for (int off = 1; off < 64; off <<= 1) {
      int src = tid - off;
      unsigned t = __shfl(S, src < 0 ? 0 : src);
      if (tid >= off) S += t;
    }
    const unsigned E = S - run;  // exclusive prefix of lane sums
#pragma unroll
    for (int j = 0; j < G; ++j) s[tid * G + j] = E + x[j];
  }
  __syncthreads();
  int r = (int)s[tid];
  __syncthreads();
  return r;
}

// ---------- exact top-50 per row: radix select + in-place sparsify ----------
__global__ __launch_bounds__(TKT)
void topk_kernel(float* __restrict__ z, int* __restrict__ idxL, float* __restrict__ valL) {
  __shared__ float sv[HID_DIM];          // 64 KiB
  __shared__ unsigned hist[256][8];      // 8 KiB, copy = tid&7 (8-way contention max)
  __shared__ unsigned sScan[256];
  __shared__ unsigned sS2[TKT];
  __shared__ unsigned sBcast[2];
  const int tid = threadIdx.x;
  const size_t row = blockIdx.x;
  float* zrow = z + row * HID_DIM;

  for (int i = tid; i < HID_DIM / 4; i += TKT)
    reinterpret_cast<float4*>(sv)[i] = reinterpret_cast<const float4*>(zrow)[i];
  __syncthreads();

  unsigned prefix = 0, Kr = TOPK;
  for (int p = 3; p >= 0; --p) {
    for (int i = tid; i < 256 * 8; i += TKT) ((unsigned*)hist)[i] = 0;
    __syncthreads();
    const int shift = p * 8;
    const unsigned pmask = (p == 3) ? 0u : (0xFFFFFFFFu << (shift + 8));
    const int cpy = tid & 7;
    for (int i = tid; i < HID_DIM; i += TKT) {
      unsigned u = key_of(sv[i]);
      if ((u & pmask) == prefix)
        atomicAdd(&hist[(u >> shift) & 0xFF][cpy], 1u);
    }
    __syncthreads();
    // wave0: sum copies + suffix scan over 256 bins (4 bins/lane)
    if (tid < 64) {
      const int b = tid * 4;
      unsigned t0 = 0, t1 = 0, t2 = 0, t3 = 0;
#pragma unroll
      for (int c = 0; c < 8; ++c) {
        t0 += hist[b + 0][c]; t1 += hist[b + 1][c];
        t2 += hist[b + 2][c]; t3 += hist[b + 3][c];
      }
      const unsigned s3 = t3, s2 = t3 + t2, s1 = s2 + t1, s0 = s1 + t0;
      unsigned L = s0;
      unsigned S = L;
#pragma unroll
      for (int off = 1; off < 64; off <<= 1) {
        int src = tid + off;
        unsigned t = __shfl(S, src > 63 ? 63 : src);
        if (src < 64) S += t;
      }
      const unsigned E = S - L;  // sum of lanes above
      sScan[b + 0] = E + s0; sScan[b + 1] = E + s1;
      sScan[b + 2] = E + s2; sScan[b + 3] = E + s3;
    }
    __syncthreads();
    if (tid < 256) {
      unsigned S = sScan[tid];
      unsigned Snext = (tid < 255) ? sScan[tid + 1] : 0u;
      if (S >= Kr && Snext < Kr) {
        sBcast[0] = prefix | ((unsigned)tid << shift);
        sBcast[1] = Kr - Snext;
      }
    }
    __syncthreads();
    prefix = sBcast[0];
    Kr = sBcast[1];
    __syncthreads();
  }
  const unsigned T = prefix;           // exact key of 50th-largest
  const int nTieKeep = (int)Kr;        // #elems == T to keep (lowest index first)
  const int cGtTotal = TOPK - nTieKeep;

  // per-thread counts over contiguous chunk (deterministic index order)
  const int CH = HID_DIM / TKT;  // 32
  const int base = tid * CH;
  int cg = 0, ct = 0;
  for (int i = 0; i < CH; ++i) {
    unsigned u = key_of(sv[base + i]);
    cg += (u > T);
    ct += (u == T);
  }
  int gs = excl_scan_blk(cg, sS2, tid);
  int ts = excl_scan_blk(ct, sS2, tid);
  for (int i = 0; i < CH; ++i) {
    float v = sv[base + i];
    unsigned u = key_of(v);
    if (u > T) {
      idxL[row * TOPK + gs] = base + i;
      valL[row * TOPK + gs] = v;
      ++gs;
    } else if (u == T) {
      if (ts < nTieKeep) {
        idxL[row * TOPK + cGtTotal + ts] = base + i;
        valL[row * TOPK + cGtTotal + ts] = v;
      }
      ++ts;
    }
  }
  __syncthreads();
  // coalesced sparse write (ties written as 0 here, fixed below)
  for (int i = tid; i < HID_DIM; i += TKT) {
    float v = sv[i];
    zrow[i] = (key_of(v) > T) ? v : 0.0f;
  }
  __syncthreads();
  if (tid < nTieKeep) {
    int gi = idxL[row * TOPK + cGtTotal + tid];
    zrow[gi] = valL[row * TOPK + cGtTotal + tid];
  }
}

// ---------- sparse decode: recon = z_sparse @ W_dec^T (bf16 weights) ----------
__global__ __launch_bounds__(256)
void decode_kernel(const int* __restrict__ idxL, const float* __restrict__ valL,
                   const u16* __restrict__ WdT, float* __restrict__ recon) {
  __shared__ int sIdx[TOPK];
  __shared__ float sVal[TOPK];
  const int tid = threadIdx.x;
  const size_t row = blockIdx.x;
  if (tid < TOPK) { sIdx[tid] = idxL[row * TOPK + tid]; sVal[tid] = valL[row * TOPK + tid]; }
  __syncthreads();
  float a0 = 0.f, a1 = 0.f, a2 = 0.f, a3 = 0.f;
  const int o = tid * 4;
  for (int j = 0; j < TOPK; ++j) {
    const ushort4 w = *reinterpret_cast<const ushort4*>(&WdT[(size_t)sIdx[j] * IN_DIM + o]);
    const float v = sVal[j];
    a0 = fmaf(v, bf2f(w.x), a0);
    a1 = fmaf(v, bf2f(w.y), a1);
    a2 = fmaf(v, bf2f(w.z), a2);
    a3 = fmaf(v, bf2f(w.w), a3);
  }
  *reinterpret_cast<float4*>(&recon[row * IN_DIM + o]) = make_float4(a0, a1, a2, a3);
}

// ---------- launch ----------
extern "C" void kernel_launch(void* const* d_in, const int* in_sizes, int n_in,
                              void* d_out, int out_size, void* d_ws, size_t ws_size,
                              hipStream_t stream) {
  const float* x  = (const float*)d_in[0];
  const float* We = (const float*)d_in[1];
  const float* Wd = (const float*)d_in[2];
  float* recon = (float*)d_out;
  float* z = recon + (size_t)B_ROWS * IN_DIM;   // outputs concatenated: recon, z

  char* ws = (char*)d_ws;
  const size_t MB = 1024ull * 1024ull;
  u16* xh = (u16*)(ws + 0 * MB);     // 16 MiB each (8192x1024 bf16)
  u16* xm = (u16*)(ws + 16 * MB);
  u16* xl = (u16*)(ws + 32 * MB);
  u16* wh = (u16*)(ws + 48 * MB);    // 32 MiB each (16384x1024 bf16)
  u16* wmm = (u16*)(ws + 80 * MB);
  u16* wl = (u16*)(ws + 112 * MB);
  u16* WdT = (u16*)(ws + 144 * MB);  // 32 MiB (bf16)
  int*   idxL = (int*)(ws + 208 * MB);  // 1.6 MiB
  float* valL = (float*)(ws + 210 * MB);// 1.6 MiB

  split3_kernel<<<2048, 256, 0, stream>>>(x, xh, xm, xl, B_ROWS * IN_DIM / 4);
  split3_kernel<<<2048, 256, 0, stream>>>(We, wh, wmm, wl, HID_DIM * IN_DIM / 4);
  transpose_kernel<<<dim3(HID_DIM / 32, IN_DIM / 32), 256, 0, stream>>>(Wd, WdT);
  gemm6_kernel<<<dim3(HID_DIM / 128, B_ROWS / 128), 256, 0, stream>>>(xh, xm, xl, wh, wmm, wl, z);
  topk_kernel<<<B_ROWS, TKT, 0, stream>>>(z, idxL, valL);
  decode_kernel<<<B_ROWS, 256, 0, stream>>>(idxL, valL, WdT, recon);
}

// Round 3
// 1618.397 us; speedup vs baseline: 1.5863x; 1.2069x over previous
//
#include <hip/hip_runtime.h>
#include <cstdint>
#include <cstddef>

#define TOPK 50
#define B_ROWS 8192
#define IN_DIM 1024
#define HID_DIM 16384
#define TKT 512   // topk threads
#define CAND_CAP 1024

typedef unsigned short u16;
typedef __attribute__((ext_vector_type(8))) short bf16x8;
typedef __attribute__((ext_vector_type(4))) float f32x4;

// ---------- helpers ----------
__device__ inline u16 f2bf_rne(float f) {
  unsigned u = __float_as_uint(f);
  unsigned r = 0x7FFFu + ((u >> 16) & 1u);
  return (u16)((u + r) >> 16);
}
__device__ inline float bf2f(u16 h) { return __uint_as_float(((unsigned)h) << 16); }
__device__ inline float ninf() { return __uint_as_float(0xFF800000u); }

__device__ inline void gload16(const void* g, void* l) {
  __builtin_amdgcn_global_load_lds(
      (const __attribute__((address_space(1))) void*)g,
      (__attribute__((address_space(3))) void*)l, 16, 0, 0);
}

// ---------- split f32 -> bf16 h/m/l ----------
__global__ __launch_bounds__(256)
void split3_kernel(const float* __restrict__ in, u16* __restrict__ h,
                   u16* __restrict__ m, u16* __restrict__ l, int n4) {
  int i = blockIdx.x * 256 + threadIdx.x;
  const int stride = gridDim.x * 256;
  for (; i < n4; i += stride) {
    const float4 f = reinterpret_cast<const float4*>(in)[i];
    float vs[4] = {f.x, f.y, f.z, f.w};
    u16 hh[4], mm[4], ll[4];
#pragma unroll
    for (int j = 0; j < 4; ++j) {
      float v = vs[j];
      u16 a = f2bf_rne(v); float fa = bf2f(a);
      u16 b = f2bf_rne(v - fa); float fb = bf2f(b);
      u16 c = f2bf_rne(v - fa - fb);
      hh[j] = a; mm[j] = b; ll[j] = c;
    }
    reinterpret_cast<ushort4*>(h)[i] = make_ushort4(hh[0], hh[1], hh[2], hh[3]);
    reinterpret_cast<ushort4*>(m)[i] = make_ushort4(mm[0], mm[1], mm[2], mm[3]);
    reinterpret_cast<ushort4*>(l)[i] = make_ushort4(ll[0], ll[1], ll[2], ll[3]);
  }
}

// ---------- transpose W_dec [1024][16384] -> WdT bf16 [16384][1024] ----------
__global__ __launch_bounds__(256)
void transpose_kernel(const float* __restrict__ Wd, u16* __restrict__ WdT) {
  __shared__ float tile[32][33];
  const int h0 = blockIdx.x * 32;
  const int o0 = blockIdx.y * 32;
  const int lx = threadIdx.x & 31;
  const int ly = threadIdx.x >> 5;  // 0..7
#pragma unroll
  for (int r = 0; r < 32; r += 8)
    tile[ly + r][lx] = Wd[(size_t)(o0 + ly + r) * HID_DIM + h0 + lx];
  __syncthreads();
#pragma unroll
  for (int r = 0; r < 32; r += 8)
    WdT[(size_t)(h0 + ly + r) * IN_DIM + o0 + lx] = f2bf_rne(tile[lx][ly + r]);
}

// ---------- GEMM: z = x @ W_enc^T via 6-term bf16 split MFMA ----------
// UNCHANGED from round 2 (bit-exact z is load-bearing for top-k selection).
__global__ __launch_bounds__(256, 2)
void gemm6_kernel(const u16* __restrict__ xh, const u16* __restrict__ xm, const u16* __restrict__ xl,
                  const u16* __restrict__ wh, const u16* __restrict__ wm, const u16* __restrict__ wl,
                  float* __restrict__ z) {
  __shared__ u16 sA[3][128 * 32];
  __shared__ u16 sB[3][128 * 32];
  const int tid = threadIdx.x;
  const int lane = tid & 63;
  const int wave = tid >> 6;
  const int wr = (wave >> 1) * 64;
  const int wc = (wave & 1) * 64;

  const int bid = blockIdx.y * gridDim.x + blockIdx.x;      // 0..8191
  const int swz = (bid & 7) * 1024 + (bid >> 3);            // bijective
  const int mg = swz >> 10;                                 // 0..7
  const int within = swz & 1023;
  const int n_idx = within >> 3;                            // 0..127
  const int m_idx = (within & 7) + mg * 8;                  // 0..63
  const int m0 = m_idx * 128;
  const int n0 = n_idx * 128;

  const int srow = tid >> 2;
  const int scol = (((tid & 3) ^ ((srow >> 1) & 3)) * 8);

  const u16* gA[3] = {xh, xm, xl};
  const u16* gB[3] = {wh, wm, wl};

  const size_t aoff = (size_t)(m0 + srow) * IN_DIM + scol;
  const size_t boff = (size_t)(n0 + srow) * IN_DIM + scol;

  f32x4 acc[4][4] = {};

  const int rsel = lane & 15;
  const int ksel = (lane >> 4) * 8;

  for (int k0 = 0; k0 < IN_DIM; k0 += 32) {
#pragma unroll
    for (int s = 0; s < 3; ++s) {
      gload16(gA[s] + aoff + k0,                 &sA[s][tid * 8]);
      gload16(gA[s] + aoff + k0 + 64 * IN_DIM,   &sA[s][2048 + tid * 8]);
      gload16(gB[s] + boff + k0,                 &sB[s][tid * 8]);
      gload16(gB[s] + boff + k0 + 64 * IN_DIM,   &sB[s][2048 + tid * 8]);
    }
    __syncthreads();
    bf16x8 a[3][4], b[3][4];
#pragma unroll
    for (int t = 0; t < 4; ++t) {
      const int ra = wr + t * 16 + rsel;
      const int rb = wc + t * 16 + rsel;
      const int ka = ksel ^ (((ra >> 1) & 3) * 8);
      const int kb = ksel ^ (((rb >> 1) & 3) * 8);
#pragma unroll
      for (int s = 0; s < 3; ++s) {
        a[s][t] = *reinterpret_cast<const bf16x8*>(&sA[s][ra * 32 + ka]);
        b[s][t] = *reinterpret_cast<const bf16x8*>(&sB[s][rb * 32 + kb]);
      }
    }
#pragma unroll
    for (int mt = 0; mt < 4; ++mt)
#pragma unroll
      for (int nt = 0; nt < 4; ++nt) {
        f32x4 c = acc[mt][nt];
        c = __builtin_amdgcn_mfma_f32_16x16x32_bf16(a[0][mt], b[0][nt], c, 0, 0, 0); // hh
        c = __builtin_amdgcn_mfma_f32_16x16x32_bf16(a[0][mt], b[1][nt], c, 0, 0, 0); // hm
        c = __builtin_amdgcn_mfma_f32_16x16x32_bf16(a[1][mt], b[0][nt], c, 0, 0, 0); // mh
        c = __builtin_amdgcn_mfma_f32_16x16x32_bf16(a[0][mt], b[2][nt], c, 0, 0, 0); // hl
        c = __builtin_amdgcn_mfma_f32_16x16x32_bf16(a[1][mt], b[1][nt], c, 0, 0, 0); // mm
        c = __builtin_amdgcn_mfma_f32_16x16x32_bf16(a[2][mt], b[0][nt], c, 0, 0, 0); // lh
        acc[mt][nt] = c;
      }
    __syncthreads();
  }
  const int col = lane & 15;
  const int r0 = (lane >> 4) * 4;
#pragma unroll
  for (int mt = 0; mt < 4; ++mt)
#pragma unroll
    for (int nt = 0; nt < 4; ++nt)
#pragma unroll
      for (int j = 0; j < 4; ++j) {
        const int rr = m0 + wr + mt * 16 + r0 + j;
        const int cc = n0 + wc + nt * 16 + col;
        z[(size_t)rr * HID_DIM + cc] = acc[mt][nt][j];
      }
}

// ---------- fused exact top-50 + sparsify + decode ----------
// Exact selection identical to radix version: top-50 by value, ties broken by
// lowest index (matches lax.top_k / np argsort stability on the kept SET).
__global__ __launch_bounds__(TKT)
void topk_decode_kernel(float* __restrict__ z, const u16* __restrict__ WdT,
                        float* __restrict__ recon) {
  __shared__ float sv[HID_DIM];        // 64 KiB
  __shared__ float cval[CAND_CAP];     // 4 KiB
  __shared__ int   cidx[CAND_CAP];     // 4 KiB
  __shared__ float sredv[TKT / 64];
  __shared__ int   sredi[TKT / 64];
  __shared__ unsigned scnt;
  __shared__ float sthr, ssig;

  const int tid = threadIdx.x;
  const int lane = tid & 63;
  const int wv = tid >> 6;
  const size_t row = blockIdx.x;
  float* zrow = z + row * HID_DIM;

  // load row + sum of squares
  float ss = 0.f;
  for (int i = tid; i < HID_DIM / 4; i += TKT) {
    float4 v = reinterpret_cast<const float4*>(zrow)[i];
    reinterpret_cast<float4*>(sv)[i] = v;
    ss = fmaf(v.x, v.x, ss); ss = fmaf(v.y, v.y, ss);
    ss = fmaf(v.z, v.z, ss); ss = fmaf(v.w, v.w, ss);
  }
#pragma unroll
  for (int off = 32; off > 0; off >>= 1) ss += __shfl_down(ss, off);
  if (lane == 0) sredv[wv] = ss;
  __syncthreads();
  if (tid == 0) {
    float t = 0.f;
#pragma unroll
    for (int w = 0; w < TKT / 64; ++w) t += sredv[w];
    float sig = sqrtf(t / (float)HID_DIM);
    ssig = sig;
    sthr = 2.2f * sig;
  }
  __syncthreads();

  // candidate collection with threshold retry
  int cnt = 0;
  bool ok = false;
  for (int att = 0; att < 4; ++att) {
    if (tid == 0) scnt = 0;
    __syncthreads();
    const float th = sthr;
    for (int i = tid; i < HID_DIM; i += TKT) {
      float v = sv[i];
      if (v > th) {
        unsigned p = atomicAdd(&scnt, 1u);
        if (p < CAND_CAP) { cval[p] = v; cidx[p] = i; }
      }
    }
    __syncthreads();
    cnt = (int)scnt;
    if (cnt >= TOPK && cnt <= CAND_CAP) { ok = true; break; }
    if (tid == 0) sthr = (cnt < TOPK) ? (sthr - 0.7f * ssig) : (sthr + 0.7f * ssig);
    __syncthreads();
  }

  if (!ok) {
    // exact fallback (never triggers for Gaussian data): 50x block argmax
    for (int r = 0; r < TOPK; ++r) {
      float bv = ninf(); int bi = 0x7FFFFFFF;
      for (int i = tid; i < HID_DIM; i += TKT) {
        float v = sv[i];
        if (v > bv || (v == bv && i < bi)) { bv = v; bi = i; }
      }
#pragma unroll
      for (int off = 32; off > 0; off >>= 1) {
        float ov = __shfl_down(bv, off); int oi = __shfl_down(bi, off);
        if (ov > bv || (ov == bv && oi < bi)) { bv = ov; bi = oi; }
      }
      if (lane == 0) { sredv[wv] = bv; sredi[wv] = bi; }
      __syncthreads();
      if (tid == 0) {
        float Bv = ninf(); int Bi = 0x7FFFFFFF;
#pragma unroll
        for (int w = 0; w < TKT / 64; ++w) {
          if (sredv[w] > Bv || (sredv[w] == Bv && sredi[w] < Bi)) { Bv = sredv[w]; Bi = sredi[w]; }
        }
        cval[r] = Bv; cidx[r] = Bi; sv[Bi] = ninf();
      }
      __syncthreads();
    }
    // restore sv entries consumed by extraction
    if (tid < TOPK) sv[cidx[tid]] = cval[tid];
    if (tid == 0) scnt = TOPK;
    __syncthreads();
    cnt = TOPK;
  }

  // pad to pow2 and bitonic sort by (value desc, index asc)
  int P2 = 64;
  while (P2 < cnt) P2 <<= 1;
  for (int i = cnt + tid; i < P2; i += TKT) { cval[i] = ninf(); cidx[i] = 0x7FFFFFFF; }
  __syncthreads();
  for (int k = 2; k <= P2; k <<= 1) {
    for (int j = k >> 1; j > 0; j >>= 1) {
      for (int i = tid; i < P2; i += TKT) {
        const int l = i ^ j;
        if (l > i) {
          float va = cval[i], vb = cval[l];
          int ia = cidx[i], ib = cidx[l];
          const bool aGreater = (va > vb) || (va == vb && ia < ib);
          const bool up = ((i & k) == 0);
          if (up ? !aGreater : aGreater) {
            cval[i] = vb; cval[l] = va;
            cidx[i] = ib; cidx[l] = ia;
          }
        }
      }
      __syncthreads();
    }
  }

  const float T = cval[TOPK - 1];
  const int lastTie = cidx[TOPK - 1];

  // sparse z write: keep v>T, plus v==T with index <= lastTie (lowest-index ties)
  for (int i = tid; i < HID_DIM; i += TKT) {
    float v = sv[i];
    zrow[i] = (v > T || (v == T && i <= lastTie)) ? v : 0.0f;
  }

  // fused decode: recon[row] = sum_j cval[j] * WdT[cidx[j]][:]
  float a0 = 0.f, a1 = 0.f;
  for (int j = 0; j < TOPK; ++j) {
    const float v = cval[j];
    const unsigned w2 = reinterpret_cast<const unsigned*>(WdT + (size_t)cidx[j] * IN_DIM)[tid];
    a0 = fmaf(v, __uint_as_float(w2 << 16), a0);
    a1 = fmaf(v, __uint_as_float(w2 & 0xFFFF0000u), a1);
  }
  reinterpret_cast<float2*>(recon + row * IN_DIM)[tid] = make_float2(a0, a1);
}

// ---------- launch ----------
extern "C" void kernel_launch(void* const* d_in, const int* in_sizes, int n_in,
                              void* d_out, int out_size, void* d_ws, size_t ws_size,
                              hipStream_t stream) {
  const float* x  = (const float*)d_in[0];
  const float* We = (const float*)d_in[1];
  const float* Wd = (const float*)d_in[2];
  float* recon = (float*)d_out;
  float* z = recon + (size_t)B_ROWS * IN_DIM;   // outputs concatenated: recon, z

  char* ws = (char*)d_ws;
  const size_t MB = 1024ull * 1024ull;
  u16* xh = (u16*)(ws + 0 * MB);     // 16 MiB each (8192x1024 bf16)
  u16* xm = (u16*)(ws + 16 * MB);
  u16* xl = (u16*)(ws + 32 * MB);
  u16* wh = (u16*)(ws + 48 * MB);    // 32 MiB each (16384x1024 bf16)
  u16* wmm = (u16*)(ws + 80 * MB);
  u16* wl = (u16*)(ws + 112 * MB);
  u16* WdT = (u16*)(ws + 144 * MB);  // 32 MiB (bf16)

  split3_kernel<<<2048, 256, 0, stream>>>(x, xh, xm, xl, B_ROWS * IN_DIM / 4);
  split3_kernel<<<2048, 256, 0, stream>>>(We, wh, wmm, wl, HID_DIM * IN_DIM / 4);
  transpose_kernel<<<dim3(HID_DIM / 32, IN_DIM / 32), 256, 0, stream>>>(Wd, WdT);
  gemm6_kernel<<<dim3(HID_DIM / 128, B_ROWS / 128), 256, 0, stream>>>(xh, xm, xl, wh, wmm, wl, z);
  topk_decode_kernel<<<B_ROWS, TKT, 0, stream>>>(z, WdT, recon);
}